// Round 8
// baseline (77.370 us; speedup 1.0000x reference)
//
#include <hip/hip_runtime.h>

#define B_   4
#define C_   256
#define CR_  64
#define H_   128
#define W_   128
#define HW_  (H_ * W_)
#define G_   16
#define GC_  16
#define KO_  144   // K*K*G = 9*16
#define EPS_ 1e-5f

typedef __bf16 bf16x8 __attribute__((ext_vector_type(8)));
typedef __bf16 bf16x2 __attribute__((ext_vector_type(2)));
typedef float  f32x4  __attribute__((ext_vector_type(4)));

#define SX 66   // LDS row stride (elements) for xs/hbuf: banks 2-way on gathers

// ---------------------------------------------------------------------------
// prep: build MFMA A-fragments (lane order: m = lane&15, kslot = 8*(lane>>4)+j;
// the kslot permutation cancels between A and B as long as both use it).
//  w1frag[kc][mt][lane][j] = bf16( w1[o=mt*16+(l&15)][c=kc*32+8*(l>>4)+j] * alpha[o] )
//  w2frag[mt][kc2][lane][j] = bf16( w2[o2=mt*16+(l&15)][cc=kc2*32+8*(l>>4)+j] )
//  bias2[o] = beta - mean*alpha
// ---------------------------------------------------------------------------
__global__ void prep_kernel(const float* __restrict__ w1,
                            const float* __restrict__ gamma,
                            const float* __restrict__ beta,
                            const float* __restrict__ mean,
                            const float* __restrict__ var,
                            const float* __restrict__ w2,
                            __bf16* __restrict__ w1frag,
                            __bf16* __restrict__ w2frag,
                            float* __restrict__ bias2) {
    int idx = blockIdx.x * 256 + threadIdx.x;
    if (idx < 16384) {                      // w1frag: [8 kc][4 mt][64 l][8 j]
        int kc = idx >> 11, r = idx & 2047;
        int mt = r >> 9, l = (r >> 3) & 63, j = r & 7;
        int o = mt * 16 + (l & 15);
        int c = kc * 32 + 8 * (l >> 4) + j;
        float alpha = gamma[o] * rsqrtf(var[o] + EPS_);
        w1frag[idx] = (__bf16)(w1[o * C_ + c] * alpha);
        if (idx < CR_) {
            float a2 = gamma[idx] * rsqrtf(var[idx] + EPS_);
            bias2[idx] = beta[idx] - mean[idx] * a2;
        }
    } else if (idx < 16384 + 9216) {        // w2frag: [9 mt][2 kc2][64 l][8 j]
        int i2 = idx - 16384;
        int mt = i2 >> 10, r = i2 & 1023;
        int kc2 = r >> 9, l = (r >> 3) & 63, j = r & 7;
        int o2 = mt * 16 + (l & 15);
        int cc = kc2 * 32 + 8 * (l >> 4) + j;
        w2frag[i2] = (__bf16)(w2[o2 * CR_ + cc]);
    }
}

// ---------------------------------------------------------------------------
// fused conv1(+BN+ReLU) + conv2 via bf16 MFMA, fp32 accumulate.
// Block = 64-pixel tile, 4 waves, grid 1024 (4 blocks/CU).
// Phase 1: h[64][64] : M=64(outs) x N=64(px) x K=256. Wave (wm,wn) owns
//   M-tiles {2wm,2wm+1} x N-tiles {2wn,2wn+1}; acc1[2][2] f32x4.
//   x staged per 32-K chunk into LDS bf16 [32][SX], double-buffered (T14).
// Phase 2: wk[144][64] : M=144 x N=64 x K=64. Wave owns N-tile=wave (16 px),
//   all 9 M-tiles; acc2[9] f32x4. B from hbuf (bf16 h in LDS).
// A-fragments read directly from global (L2-hot, pre-fragged by prep).
// D layout (verified): col(n)=lane&15, row(m)=4*(lane>>4)+reg.
// ---------------------------------------------------------------------------
__global__ __launch_bounds__(256, 4) void conv12_kernel(
        const float* __restrict__ x,
        const __bf16* __restrict__ w1frag,
        const float* __restrict__ bias2,
        const __bf16* __restrict__ w2frag,
        const float* __restrict__ b2,
        float* __restrict__ wk) {
    __shared__ __bf16 xs[2 * 32 * SX];     // 8.4 KB double-buffered x chunk
    __shared__ __bf16 hbuf[CR_ * SX];      // 8.4 KB h tile (bf16)

    const int tid  = threadIdx.x;
    const int lane = tid & 63;
    const int wave = tid >> 6;
    const int wm = wave >> 1, wn = wave & 1;
    const int g = lane >> 4, n = lane & 15;

    const int px0 = blockIdx.x * 64;
    const int b   = px0 >> 14;
    const int hw0 = px0 & (HW_ - 1);

    const float* xb = x + (size_t)b * C_ * HW_ + hw0;
    const int krow = tid >> 3;             // 0..31 (k row within chunk)
    const int t8   = tid & 7;              // 0..7  (two float4 segs per row)

    // ---- stage chunk 0 into buf 0 ----
    {
        float4 v0 = *(const float4*)&xb[(size_t)krow * HW_ + 4 * t8];
        float4 v1 = *(const float4*)&xb[(size_t)krow * HW_ + 32 + 4 * t8];
        __bf16* d0 = &xs[krow * SX + 4 * t8];
        __bf16* d1 = &xs[krow * SX + 32 + 4 * t8];
        *(bf16x2*)&d0[0] = bf16x2{(__bf16)v0.x, (__bf16)v0.y};
        *(bf16x2*)&d0[2] = bf16x2{(__bf16)v0.z, (__bf16)v0.w};
        *(bf16x2*)&d1[0] = bf16x2{(__bf16)v1.x, (__bf16)v1.y};
        *(bf16x2*)&d1[2] = bf16x2{(__bf16)v1.z, (__bf16)v1.w};
    }
    __syncthreads();

    // ======================= phase 1 ============================
    f32x4 acc1[2][2];
#pragma unroll
    for (int m = 0; m < 2; ++m)
#pragma unroll
        for (int t = 0; t < 2; ++t) acc1[m][t] = f32x4{0.f, 0.f, 0.f, 0.f};

    for (int kc = 0; kc < 8; ++kc) {
        const int buf = kc & 1;
        float4 nf0, nf1;
        if (kc < 7) {   // issue next chunk's loads early (hide HBM latency)
            nf0 = *(const float4*)&xb[(size_t)(32 * (kc + 1) + krow) * HW_ + 4 * t8];
            nf1 = *(const float4*)&xb[(size_t)(32 * (kc + 1) + krow) * HW_ + 32 + 4 * t8];
        }
        // A fragments (global, L2-hot, pre-fragged)
        bf16x8 a0 = *(const bf16x8*)&w1frag[((kc * 4 + 2 * wm + 0) * 64 + lane) * 8];
        bf16x8 a1 = *(const bf16x8*)&w1frag[((kc * 4 + 2 * wm + 1) * 64 + lane) * 8];
        // B fragments: gather bf16 from xs (kslot = 8g+j, matches A's layout)
        const int base = buf * (32 * SX);
        bf16x8 b0, b1;
#pragma unroll
        for (int j = 0; j < 8; ++j) {
            b0[j] = xs[base + (8 * g + j) * SX + (2 * wn + 0) * 16 + n];
            b1[j] = xs[base + (8 * g + j) * SX + (2 * wn + 1) * 16 + n];
        }
        acc1[0][0] = __builtin_amdgcn_mfma_f32_16x16x32_bf16(a0, b0, acc1[0][0], 0, 0, 0);
        acc1[0][1] = __builtin_amdgcn_mfma_f32_16x16x32_bf16(a0, b1, acc1[0][1], 0, 0, 0);
        acc1[1][0] = __builtin_amdgcn_mfma_f32_16x16x32_bf16(a1, b0, acc1[1][0], 0, 0, 0);
        acc1[1][1] = __builtin_amdgcn_mfma_f32_16x16x32_bf16(a1, b1, acc1[1][1], 0, 0, 0);

        if (kc < 7) {   // write next chunk into other buffer
            __bf16* d0 = &xs[(buf ^ 1) * (32 * SX) + krow * SX + 4 * t8];
            __bf16* d1 = &xs[(buf ^ 1) * (32 * SX) + krow * SX + 32 + 4 * t8];
            *(bf16x2*)&d0[0] = bf16x2{(__bf16)nf0.x, (__bf16)nf0.y};
            *(bf16x2*)&d0[2] = bf16x2{(__bf16)nf0.z, (__bf16)nf0.w};
            *(bf16x2*)&d1[0] = bf16x2{(__bf16)nf1.x, (__bf16)nf1.y};
            *(bf16x2*)&d1[2] = bf16x2{(__bf16)nf1.z, (__bf16)nf1.w};
        }
        __syncthreads();
    }

    // bias + relu -> hbuf (bf16). D elem: o = Mt*16+4g+j, px = Nt*16+n
#pragma unroll
    for (int m = 0; m < 2; ++m) {
        const int Mo = (2 * wm + m) * 16 + 4 * g;
        float4 bv = *(const float4*)&bias2[Mo];
        float bj[4] = {bv.x, bv.y, bv.z, bv.w};
#pragma unroll
        for (int t = 0; t < 2; ++t) {
            const int px = (2 * wn + t) * 16 + n;
#pragma unroll
            for (int j = 0; j < 4; ++j) {
                hbuf[(Mo + j) * SX + px] = (__bf16)fmaxf(acc1[m][t][j] + bj[j], 0.f);
            }
        }
    }
    __syncthreads();

    // ======================= phase 2 ============================
    f32x4 acc2[9];
#pragma unroll
    for (int m = 0; m < 9; ++m) acc2[m] = f32x4{0.f, 0.f, 0.f, 0.f};

#pragma unroll
    for (int kc2 = 0; kc2 < 2; ++kc2) {
        bf16x8 hb;
#pragma unroll
        for (int j = 0; j < 8; ++j)
            hb[j] = hbuf[(kc2 * 32 + 8 * g + j) * SX + wave * 16 + n];
#pragma unroll
        for (int mt = 0; mt < 9; ++mt) {
            bf16x8 a = *(const bf16x8*)&w2frag[((mt * 2 + kc2) * 64 + lane) * 8];
            acc2[mt] = __builtin_amdgcn_mfma_f32_16x16x32_bf16(a, hb, acc2[mt], 0, 0, 0);
        }
    }

    // store wk: o2 = mt*16+4g+j, px = wave*16+n
    float* wkb = wk + (size_t)b * KO_ * HW_ + hw0 + wave * 16 + n;
#pragma unroll
    for (int mt = 0; mt < 9; ++mt) {
        const int o0 = mt * 16 + 4 * g;
        float4 bv = *(const float4*)&b2[o0];
        float bj[4] = {bv.x, bv.y, bv.z, bv.w};
#pragma unroll
        for (int j = 0; j < 4; ++j)
            wkb[(size_t)(o0 + j) * HW_] = acc2[mt][j] + bj[j];
    }
}

// ---------------------------------------------------------------------------
// involution: out[b][g*16+cc][hw] = sum_k wk[b][g*9+k][hw] * x[b][g*16+cc][hw+off(k)]
// ---------------------------------------------------------------------------
__global__ __launch_bounds__(256) void inv_kernel(const float* __restrict__ x,
                                                  const float* __restrict__ wk,
                                                  float* __restrict__ out) {
    const int tid = blockIdx.x * 256 + threadIdx.x;   // 0 .. B*G*HW-1
    const int hw  = tid & (HW_ - 1);
    const int g   = (tid >> 14) & (G_ - 1);
    const int b   = tid >> 18;
    const int h   = hw >> 7;
    const int w   = hw & (W_ - 1);

    float wk9[9];
    const float* wkp = wk + ((size_t)b * KO_ + g * 9) * HW_ + hw;
#pragma unroll
    for (int k = 0; k < 9; ++k) wk9[k] = wkp[(size_t)k * HW_];

    const float* xp = x + ((size_t)b * C_ + g * GC_) * HW_ + hw;
    float* op       = out + ((size_t)b * C_ + g * GC_) * HW_ + hw;

    const bool hok0 = (h > 0), hok2 = (h < H_ - 1);
    const bool wok0 = (w > 0), wok2 = (w < W_ - 1);

#pragma unroll 4
    for (int cc = 0; cc < GC_; ++cc) {
        const float* xc = xp + (size_t)cc * HW_;
        float acc = 0.f;
        if (hok0) {
            float xm = wok0 ? xc[-W_ - 1] : 0.f;
            float x0 = xc[-W_];
            float xq = wok2 ? xc[-W_ + 1] : 0.f;
            acc = fmaf(wk9[0], xm, acc);
            acc = fmaf(wk9[1], x0, acc);
            acc = fmaf(wk9[2], xq, acc);
        }
        {
            float xm = wok0 ? xc[-1] : 0.f;
            float x0 = xc[0];
            float xq = wok2 ? xc[1] : 0.f;
            acc = fmaf(wk9[3], xm, acc);
            acc = fmaf(wk9[4], x0, acc);
            acc = fmaf(wk9[5], xq, acc);
        }
        if (hok2) {
            float xm = wok0 ? xc[W_ - 1] : 0.f;
            float x0 = xc[W_];
            float xq = wok2 ? xc[W_ + 1] : 0.f;
            acc = fmaf(wk9[6], xm, acc);
            acc = fmaf(wk9[7], x0, acc);
            acc = fmaf(wk9[8], xq, acc);
        }
        op[(size_t)cc * HW_] = acc;
    }
}

// ---------------------------------------------------------------------------
extern "C" void kernel_launch(void* const* d_in, const int* in_sizes, int n_in,
                              void* d_out, int out_size, void* d_ws, size_t ws_size,
                              hipStream_t stream) {
    const float* x     = (const float*)d_in[0];
    const float* w1    = (const float*)d_in[1];
    const float* gamma = (const float*)d_in[2];
    const float* beta  = (const float*)d_in[3];
    const float* mean  = (const float*)d_in[4];
    const float* var   = (const float*)d_in[5];
    const float* w2    = (const float*)d_in[6];
    const float* b2    = (const float*)d_in[7];
    float* out = (float*)d_out;

    char* ws = (char*)d_ws;
    __bf16* w1frag = (__bf16*)(ws);                 // 32 KB [8][4][64][8]
    __bf16* w2frag = (__bf16*)(ws + (32 << 10));    // 18 KB [9][2][64][8]
    float*  bias2  = (float*)(ws + (56 << 10));     // 256 B
    float*  wkbuf  = (float*)(ws + (1 << 20));      // 36 MB [B][144][HW]

    hipLaunchKernelGGL(prep_kernel, dim3(100), dim3(256), 0, stream,
                       w1, gamma, beta, mean, var, w2, w1frag, w2frag, bias2);
    hipLaunchKernelGGL(conv12_kernel, dim3(1024), dim3(256), 0, stream,
                       x, w1frag, bias2, w2frag, b2, wkbuf);
    hipLaunchKernelGGL(inv_kernel, dim3(4096), dim3(256), 0, stream,
                       x, wkbuf, out);
}

// Round 9
// 70.486 us; speedup vs baseline: 1.0977x; 1.0977x over previous
//
#include <hip/hip_runtime.h>

#define B_   4
#define C_   256
#define CR_  64
#define H_   128
#define W_   128
#define HW_  (H_ * W_)
#define G_   16
#define GC_  16
#define KO_  144   // K*K*G = 9*16
#define EPS_ 1e-5f

typedef __bf16 bf16x8 __attribute__((ext_vector_type(8)));
typedef __bf16 bf16x2 __attribute__((ext_vector_type(2)));
typedef float  f32x4  __attribute__((ext_vector_type(4)));

#define SX 66   // LDS row stride (elements) for xs/hbuf: banks 2-way on gathers

// ---------------------------------------------------------------------------
// prep: build MFMA A-fragments (lane order: m = lane&15, kslot = 8*(lane>>4)+j;
// the kslot permutation cancels between A and B as long as both use it).
// ---------------------------------------------------------------------------
__global__ void prep_kernel(const float* __restrict__ w1,
                            const float* __restrict__ gamma,
                            const float* __restrict__ beta,
                            const float* __restrict__ mean,
                            const float* __restrict__ var,
                            const float* __restrict__ w2,
                            __bf16* __restrict__ w1frag,
                            __bf16* __restrict__ w2frag,
                            float* __restrict__ bias2) {
    int idx = blockIdx.x * 256 + threadIdx.x;
    if (idx < 16384) {                      // w1frag: [8 kc][4 mt][64 l][8 j]
        int kc = idx >> 11, r = idx & 2047;
        int mt = r >> 9, l = (r >> 3) & 63, j = r & 7;
        int o = mt * 16 + (l & 15);
        int c = kc * 32 + 8 * (l >> 4) + j;
        float alpha = gamma[o] * rsqrtf(var[o] + EPS_);
        w1frag[idx] = (__bf16)(w1[o * C_ + c] * alpha);
        if (idx < CR_) {
            float a2 = gamma[idx] * rsqrtf(var[idx] + EPS_);
            bias2[idx] = beta[idx] - mean[idx] * a2;
        }
    } else if (idx < 16384 + 9216) {        // w2frag: [9 mt][2 kc2][64 l][8 j]
        int i2 = idx - 16384;
        int mt = i2 >> 10, r = i2 & 1023;
        int kc2 = r >> 9, l = (r >> 3) & 63, j = r & 7;
        int o2 = mt * 16 + (l & 15);
        int cc = kc2 * 32 + 8 * (l >> 4) + j;
        w2frag[i2] = (__bf16)(w2[o2 * CR_ + cc]);
    }
}

// ---------------------------------------------------------------------------
// fused conv1(+BN+ReLU) + conv2 via bf16 MFMA, fp32 accumulate.
// (unchanged from R4 — ~22 us, near its x+wk HBM floor)
// ---------------------------------------------------------------------------
__global__ __launch_bounds__(256, 4) void conv12_kernel(
        const float* __restrict__ x,
        const __bf16* __restrict__ w1frag,
        const float* __restrict__ bias2,
        const __bf16* __restrict__ w2frag,
        const float* __restrict__ b2,
        float* __restrict__ wk) {
    __shared__ __bf16 xs[2 * 32 * SX];     // 8.4 KB double-buffered x chunk
    __shared__ __bf16 hbuf[CR_ * SX];      // 8.4 KB h tile (bf16)

    const int tid  = threadIdx.x;
    const int lane = tid & 63;
    const int wave = tid >> 6;
    const int wm = wave >> 1, wn = wave & 1;
    const int g = lane >> 4, n = lane & 15;

    const int px0 = blockIdx.x * 64;
    const int b   = px0 >> 14;
    const int hw0 = px0 & (HW_ - 1);

    const float* xb = x + (size_t)b * C_ * HW_ + hw0;
    const int krow = tid >> 3;             // 0..31 (k row within chunk)
    const int t8   = tid & 7;              // 0..7  (two float4 segs per row)

    // ---- stage chunk 0 into buf 0 ----
    {
        float4 v0 = *(const float4*)&xb[(size_t)krow * HW_ + 4 * t8];
        float4 v1 = *(const float4*)&xb[(size_t)krow * HW_ + 32 + 4 * t8];
        __bf16* d0 = &xs[krow * SX + 4 * t8];
        __bf16* d1 = &xs[krow * SX + 32 + 4 * t8];
        *(bf16x2*)&d0[0] = bf16x2{(__bf16)v0.x, (__bf16)v0.y};
        *(bf16x2*)&d0[2] = bf16x2{(__bf16)v0.z, (__bf16)v0.w};
        *(bf16x2*)&d1[0] = bf16x2{(__bf16)v1.x, (__bf16)v1.y};
        *(bf16x2*)&d1[2] = bf16x2{(__bf16)v1.z, (__bf16)v1.w};
    }
    __syncthreads();

    // ======================= phase 1 ============================
    f32x4 acc1[2][2];
#pragma unroll
    for (int m = 0; m < 2; ++m)
#pragma unroll
        for (int t = 0; t < 2; ++t) acc1[m][t] = f32x4{0.f, 0.f, 0.f, 0.f};

    for (int kc = 0; kc < 8; ++kc) {
        const int buf = kc & 1;
        float4 nf0, nf1;
        if (kc < 7) {   // issue next chunk's loads early (hide HBM latency)
            nf0 = *(const float4*)&xb[(size_t)(32 * (kc + 1) + krow) * HW_ + 4 * t8];
            nf1 = *(const float4*)&xb[(size_t)(32 * (kc + 1) + krow) * HW_ + 32 + 4 * t8];
        }
        // A fragments (global, L2-hot, pre-fragged)
        bf16x8 a0 = *(const bf16x8*)&w1frag[((kc * 4 + 2 * wm + 0) * 64 + lane) * 8];
        bf16x8 a1 = *(const bf16x8*)&w1frag[((kc * 4 + 2 * wm + 1) * 64 + lane) * 8];
        // B fragments: gather bf16 from xs (kslot = 8g+j, matches A's layout)
        const int base = buf * (32 * SX);
        bf16x8 b0, b1;
#pragma unroll
        for (int j = 0; j < 8; ++j) {
            b0[j] = xs[base + (8 * g + j) * SX + (2 * wn + 0) * 16 + n];
            b1[j] = xs[base + (8 * g + j) * SX + (2 * wn + 1) * 16 + n];
        }
        acc1[0][0] = __builtin_amdgcn_mfma_f32_16x16x32_bf16(a0, b0, acc1[0][0], 0, 0, 0);
        acc1[0][1] = __builtin_amdgcn_mfma_f32_16x16x32_bf16(a0, b1, acc1[0][1], 0, 0, 0);
        acc1[1][0] = __builtin_amdgcn_mfma_f32_16x16x32_bf16(a1, b0, acc1[1][0], 0, 0, 0);
        acc1[1][1] = __builtin_amdgcn_mfma_f32_16x16x32_bf16(a1, b1, acc1[1][1], 0, 0, 0);

        if (kc < 7) {   // write next chunk into other buffer
            __bf16* d0 = &xs[(buf ^ 1) * (32 * SX) + krow * SX + 4 * t8];
            __bf16* d1 = &xs[(buf ^ 1) * (32 * SX) + krow * SX + 32 + 4 * t8];
            *(bf16x2*)&d0[0] = bf16x2{(__bf16)nf0.x, (__bf16)nf0.y};
            *(bf16x2*)&d0[2] = bf16x2{(__bf16)nf0.z, (__bf16)nf0.w};
            *(bf16x2*)&d1[0] = bf16x2{(__bf16)nf1.x, (__bf16)nf1.y};
            *(bf16x2*)&d1[2] = bf16x2{(__bf16)nf1.z, (__bf16)nf1.w};
        }
        __syncthreads();
    }

    // bias + relu -> hbuf (bf16). D elem: o = Mt*16+4g+j, px = Nt*16+n
#pragma unroll
    for (int m = 0; m < 2; ++m) {
        const int Mo = (2 * wm + m) * 16 + 4 * g;
        float4 bv = *(const float4*)&bias2[Mo];
        float bj[4] = {bv.x, bv.y, bv.z, bv.w};
#pragma unroll
        for (int t = 0; t < 2; ++t) {
            const int px = (2 * wn + t) * 16 + n;
#pragma unroll
            for (int j = 0; j < 4; ++j) {
                hbuf[(Mo + j) * SX + px] = (__bf16)fmaxf(acc1[m][t][j] + bj[j], 0.f);
            }
        }
    }
    __syncthreads();

    // ======================= phase 2 ============================
    f32x4 acc2[9];
#pragma unroll
    for (int m = 0; m < 9; ++m) acc2[m] = f32x4{0.f, 0.f, 0.f, 0.f};

#pragma unroll
    for (int kc2 = 0; kc2 < 2; ++kc2) {
        bf16x8 hb;
#pragma unroll
        for (int j = 0; j < 8; ++j)
            hb[j] = hbuf[(kc2 * 32 + 8 * g + j) * SX + wave * 16 + n];
#pragma unroll
        for (int mt = 0; mt < 9; ++mt) {
            bf16x8 a = *(const bf16x8*)&w2frag[((mt * 2 + kc2) * 64 + lane) * 8];
            acc2[mt] = __builtin_amdgcn_mfma_f32_16x16x32_bf16(a, hb, acc2[mt], 0, 0, 0);
        }
    }

    // store wk: o2 = mt*16+4g+j, px = wave*16+n
    float* wkb = wk + (size_t)b * KO_ * HW_ + hw0 + wave * 16 + n;
#pragma unroll
    for (int mt = 0; mt < 9; ++mt) {
        const int o0 = mt * 16 + 4 * g;
        float4 bv = *(const float4*)&b2[o0];
        float bj[4] = {bv.x, bv.y, bv.z, bv.w};
#pragma unroll
        for (int j = 0; j < 4; ++j)
            wkb[(size_t)(o0 + j) * HW_] = acc2[mt][j] + bj[j];
    }
}

// ---------------------------------------------------------------------------
// involution, float4 form: thread = (b, g, 4 consecutive pixels in a row).
// wk: 9 x float4 loads. Per x row: 1 aligned float4 + 2 exec-guarded edge
// dwords; +-1 taps come from register selects. 3.6x fewer vmem issues vs
// the scalar version, same HBM bytes.
// ---------------------------------------------------------------------------
__global__ __launch_bounds__(256) void inv_kernel(const float* __restrict__ x,
                                                  const float* __restrict__ wk,
                                                  float* __restrict__ out) {
    const int q   = blockIdx.x * 256 + threadIdx.x;   // quad index
    const int hw  = (q & 4095) << 2;
    const int g   = (q >> 12) & (G_ - 1);
    const int b   = q >> 16;
    const int h   = hw >> 7;
    const int w0  = hw & (W_ - 1);

    float4 wk4[9];
    const float* wkp = wk + ((size_t)b * KO_ + g * 9) * HW_ + hw;
#pragma unroll
    for (int k = 0; k < 9; ++k) wk4[k] = *(const float4*)&wkp[(size_t)k * HW_];

    const float* xp = x + ((size_t)b * C_ + g * GC_) * HW_ + hw;   // center row, w0
    float* op       = out + ((size_t)b * C_ + g * GC_) * HW_ + hw;

    const bool hok0 = (h > 0), hok2 = (h < H_ - 1);
    const bool wl   = (w0 > 0), wr = (w0 < W_ - 4);

#pragma unroll 2
    for (int cc = 0; cc < GC_; ++cc) {
        const float* xc = xp + (size_t)cc * HW_;
        float4 acc = {0.f, 0.f, 0.f, 0.f};
#pragma unroll
        for (int r = 0; r < 3; ++r) {
            if ((r == 0 && !hok0) || (r == 2 && !hok2)) continue;
            const float* rp = xc + (r - 1) * W_;
            float4 c = *(const float4*)rp;
            float lm = 0.f, rm = 0.f;
            if (wl) lm = rp[-1];
            if (wr) rm = rp[4];
            const float k0 = ((const float*)&wk4[3 * r + 0])[0] * 0.f +  // silence unused-warn path
                             0.f;  // (placeholder, real taps below)
            float4 t0 = wk4[3 * r + 0];
            float4 t1 = wk4[3 * r + 1];
            float4 t2 = wk4[3 * r + 2];
            acc.x = fmaf(t0.x, lm,  acc.x);
            acc.y = fmaf(t0.y, c.x, acc.y);
            acc.z = fmaf(t0.z, c.y, acc.z);
            acc.w = fmaf(t0.w, c.z, acc.w);
            acc.x = fmaf(t1.x, c.x, acc.x);
            acc.y = fmaf(t1.y, c.y, acc.y);
            acc.z = fmaf(t1.z, c.z, acc.z);
            acc.w = fmaf(t1.w, c.w, acc.w);
            acc.x = fmaf(t2.x, c.y, acc.x);
            acc.y = fmaf(t2.y, c.z, acc.y);
            acc.z = fmaf(t2.z, c.w, acc.z);
            acc.w = fmaf(t2.w, rm,  acc.w);
            (void)k0;
        }
        *(float4*)&op[(size_t)cc * HW_] = acc;
    }
}

// ---------------------------------------------------------------------------
extern "C" void kernel_launch(void* const* d_in, const int* in_sizes, int n_in,
                              void* d_out, int out_size, void* d_ws, size_t ws_size,
                              hipStream_t stream) {
    const float* x     = (const float*)d_in[0];
    const float* w1    = (const float*)d_in[1];
    const float* gamma = (const float*)d_in[2];
    const float* beta  = (const float*)d_in[3];
    const float* mean  = (const float*)d_in[4];
    const float* var   = (const float*)d_in[5];
    const float* w2    = (const float*)d_in[6];
    const float* b2    = (const float*)d_in[7];
    float* out = (float*)d_out;

    char* ws = (char*)d_ws;
    __bf16* w1frag = (__bf16*)(ws);                 // 32 KB [8][4][64][8]
    __bf16* w2frag = (__bf16*)(ws + (32 << 10));    // 18 KB [9][2][64][8]
    float*  bias2  = (float*)(ws + (56 << 10));     // 256 B
    float*  wkbuf  = (float*)(ws + (1 << 20));      // 36 MB [B][144][HW]

    hipLaunchKernelGGL(prep_kernel, dim3(100), dim3(256), 0, stream,
                       w1, gamma, beta, mean, var, w2, w1frag, w2frag, bias2);
    hipLaunchKernelGGL(conv12_kernel, dim3(1024), dim3(256), 0, stream,
                       x, w1frag, bias2, w2frag, b2, wkbuf);
    hipLaunchKernelGGL(inv_kernel, dim3(1024), dim3(256), 0, stream,
                       x, wkbuf, out);
}